// Round 1
// baseline (612.973 us; speedup 1.0000x reference)
//
#include <hip/hip_runtime.h>
#include <hip/hip_bf16.h>
#include <cstdint>

// MoE feed-forward, routed top-2 of 8 experts.
// B=2 S=2048 D=1024 F=2048 E=8 K=2.
// Pipeline: zero -> gating(fp32) -> scan -> scatter -> cvt(bf16) -> GEMM1(W1,W2 fused + SiLU) -> GEMM2(W3 + prob*atomicAdd)

#define Dd 1024
#define Ff 2048
#define Ee 8
#define TOK 4096
#define PAIRS 8192

typedef __attribute__((ext_vector_type(8))) short short8;
typedef __attribute__((ext_vector_type(4))) float floatx4;

__device__ __forceinline__ unsigned short f2bf(float f) {
    unsigned int u = __float_as_uint(f);
    unsigned int r = (u + 0x7FFFu + ((u >> 16) & 1u)) >> 16;
    return (unsigned short)r;
}

// ---------------- zero out + meta ----------------
__global__ void zero_kernel(float* __restrict__ out, int n4, int* __restrict__ meta) {
    int i = blockIdx.x * blockDim.x + threadIdx.x;
    if (i < n4) reinterpret_cast<float4*>(out)[i] = make_float4(0.f, 0.f, 0.f, 0.f);
    if (i < 32) meta[i] = 0;   // meta: [0..7]=counts [8..15]=cursor [16..23]=base
}

// ---------------- gating: fp32 scores, top-2, softmax ----------------
__global__ void gating_kernel(const float* __restrict__ x, const float* __restrict__ Wg,
                              int* __restrict__ tok_idx, float* __restrict__ tok_prob,
                              int* __restrict__ meta) {
    int lane = threadIdx.x & 63;
    int w = threadIdx.x >> 6;
    int t = blockIdx.x * 4 + w;

    float xr[16];
    const float* xp = x + (size_t)t * Dd;
#pragma unroll
    for (int i = 0; i < 16; i++) xr[i] = xp[lane + i * 64];

    float sc[Ee];
    for (int e = 0; e < Ee; e++) {
        const float* wp = Wg + (size_t)e * Dd;
        float p = 0.f;
#pragma unroll
        for (int i = 0; i < 16; i++) p += xr[i] * wp[lane + i * 64];
        for (int off = 32; off > 0; off >>= 1) p += __shfl_xor(p, off);
        sc[e] = p;
    }
    if (lane == 0) {
        int e1 = 0, e2 = 0;
        float b1 = -1e30f, b2 = -1e30f;
        for (int e = 0; e < Ee; e++) {
            float s = sc[e];
            if (s > b1) { b2 = b1; e2 = e1; b1 = s; e1 = e; }
            else if (s > b2) { b2 = s; e2 = e; }
        }
        float p1 = 1.f / (1.f + expf(b2 - b1));
        float p2 = 1.f - p1;
        tok_idx[t * 2 + 0] = e1;
        tok_idx[t * 2 + 1] = e2;
        tok_prob[t * 2 + 0] = p1;
        tok_prob[t * 2 + 1] = p2;
        atomicAdd(&meta[e1], 1);
        atomicAdd(&meta[e2], 1);
    }
}

// ---------------- exclusive scan of counts -> base ----------------
__global__ void scan_kernel(int* __restrict__ meta) {
    int b = 0;
    for (int e = 0; e < Ee; e++) { meta[16 + e] = b; b += meta[e]; }
}

// ---------------- scatter tokens into per-expert lists ----------------
__global__ void scatter_kernel(const int* __restrict__ tok_idx, const float* __restrict__ tok_prob,
                               int* __restrict__ meta,
                               int* __restrict__ list_tok, float* __restrict__ list_prob) {
    int t = blockIdx.x * blockDim.x + threadIdx.x;
    if (t >= TOK) return;
    for (int k = 0; k < 2; k++) {
        int e = tok_idx[t * 2 + k];
        int pos = meta[16 + e] + atomicAdd(&meta[8 + e], 1);
        list_tok[pos] = t;
        list_prob[pos] = tok_prob[t * 2 + k];
    }
}

// ---------------- fp32 -> bf16 convert ----------------
__global__ void cvt_kernel(const float* __restrict__ src, unsigned short* __restrict__ dst, int n4) {
    int i = blockIdx.x * blockDim.x + threadIdx.x;
    if (i >= n4) return;
    float4 v = reinterpret_cast<const float4*>(src)[i];
    uint2 o;
    o.x = (unsigned)f2bf(v.x) | ((unsigned)f2bf(v.y) << 16);
    o.y = (unsigned)f2bf(v.z) | ((unsigned)f2bf(v.w) << 16);
    reinterpret_cast<uint2*>(dst)[i] = o;
}

// ---------------- LDS staging helpers (16 elems / thread) ----------------
__device__ __forceinline__ void stage16(unsigned short* dst, const unsigned short* src) {
    const uint4* s = reinterpret_cast<const uint4*>(src);
    uint4* d = reinterpret_cast<uint4*>(dst);
    d[0] = s[0];
    d[1] = s[1];
}
__device__ __forceinline__ void stage16(unsigned short* dst, const float* src) {
    const float4* s = reinterpret_cast<const float4*>(src);
    float4 v0 = s[0], v1 = s[1], v2 = s[2], v3 = s[3];
    uint4 o0, o1;
    o0.x = (unsigned)f2bf(v0.x) | ((unsigned)f2bf(v0.y) << 16);
    o0.y = (unsigned)f2bf(v0.z) | ((unsigned)f2bf(v0.w) << 16);
    o0.z = (unsigned)f2bf(v1.x) | ((unsigned)f2bf(v1.y) << 16);
    o0.w = (unsigned)f2bf(v1.z) | ((unsigned)f2bf(v1.w) << 16);
    o1.x = (unsigned)f2bf(v2.x) | ((unsigned)f2bf(v2.y) << 16);
    o1.y = (unsigned)f2bf(v2.z) | ((unsigned)f2bf(v2.w) << 16);
    o1.z = (unsigned)f2bf(v3.x) | ((unsigned)f2bf(v3.y) << 16);
    o1.w = (unsigned)f2bf(v3.z) | ((unsigned)f2bf(v3.w) << 16);
    uint4* d = reinterpret_cast<uint4*>(dst);
    d[0] = o0;
    d[1] = o1;
}

// ---------------- GEMM1: hidden = silu(x W1^T) * (x W2^T), routed ----------------
template <typename WT>
__global__ __launch_bounds__(256, 2) void gemm1_kernel(
    const unsigned short* __restrict__ xb,
    const WT* __restrict__ W1, const WT* __restrict__ W2,
    unsigned short* __restrict__ hidden,
    const int* __restrict__ list_tok, const int* __restrict__ meta) {
    int e = blockIdx.z;
    int cnt = meta[e];
    int m0 = blockIdx.y * 128;
    if (m0 >= cnt) return;
    int bs = meta[16 + e];
    int n0 = blockIdx.x * 128;

    __shared__ unsigned short sA[128 * 32];
    __shared__ unsigned short sB1[128 * 32];
    __shared__ unsigned short sB2[128 * 32];

    int tid = threadIdx.x;
    int row = tid >> 1;
    int half = tid & 1;
    int colb = half * 16;

    int r = m0 + row;
    if (r >= cnt) r = cnt - 1;
    const unsigned short* aptr = xb + (size_t)list_tok[bs + r] * Dd + colb;
    const WT* b1ptr = W1 + ((size_t)e * Ff + n0 + row) * Dd + colb;
    const WT* b2ptr = W2 + ((size_t)e * Ff + n0 + row) * Dd + colb;

    int lane = tid & 63;
    int w = tid >> 6;
    int wm = w >> 1, wn = w & 1;
    int lane15 = lane & 15, quad = lane >> 4;

    floatx4 acc1[4][4] = {};
    floatx4 acc2[4][4] = {};

    unsigned short* sAw = &sA[row * 32 + colb];
    unsigned short* sB1w = &sB1[row * 32 + colb];
    unsigned short* sB2w = &sB2[row * 32 + colb];
    const unsigned short* sAr = &sA[(wm * 64 + lane15) * 32 + quad * 8];
    const unsigned short* sB1r = &sB1[(wn * 64 + lane15) * 32 + quad * 8];
    const unsigned short* sB2r = &sB2[(wn * 64 + lane15) * 32 + quad * 8];

    for (int k0 = 0; k0 < Dd; k0 += 32) {
        stage16(sAw, aptr + k0);
        stage16(sB1w, b1ptr + k0);
        stage16(sB2w, b2ptr + k0);
        __syncthreads();
        short8 af[4], bf1[4], bf2[4];
#pragma unroll
        for (int i = 0; i < 4; i++) {
            af[i]  = *reinterpret_cast<const short8*>(sAr + i * 16 * 32);
            bf1[i] = *reinterpret_cast<const short8*>(sB1r + i * 16 * 32);
            bf2[i] = *reinterpret_cast<const short8*>(sB2r + i * 16 * 32);
        }
#pragma unroll
        for (int mi = 0; mi < 4; mi++)
#pragma unroll
            for (int ni = 0; ni < 4; ni++) {
                acc1[mi][ni] = __builtin_amdgcn_mfma_f32_16x16x32_bf16(af[mi], bf1[ni], acc1[mi][ni], 0, 0, 0);
                acc2[mi][ni] = __builtin_amdgcn_mfma_f32_16x16x32_bf16(af[mi], bf2[ni], acc2[mi][ni], 0, 0, 0);
            }
        __syncthreads();
    }

#pragma unroll
    for (int mi = 0; mi < 4; mi++) {
#pragma unroll
        for (int i = 0; i < 4; i++) {
            int rr = m0 + wm * 64 + mi * 16 + quad * 4 + i;
            if (rr < cnt) {
                unsigned short* hp = hidden + (size_t)(bs + rr) * Ff + n0 + wn * 64;
#pragma unroll
                for (int ni = 0; ni < 4; ni++) {
                    float h1 = acc1[mi][ni][i];
                    float h2 = acc2[mi][ni][i];
                    float hv = h1 / (1.f + expf(-h1)) * h2;
                    hp[ni * 16 + lane15] = f2bf(hv);
                }
            }
        }
    }
}

// ---------------- GEMM2: out[tok] += prob * (hidden W3^T), routed ----------------
template <typename WT>
__global__ __launch_bounds__(256, 2) void gemm2_kernel(
    const unsigned short* __restrict__ hidden,
    const WT* __restrict__ W3,
    float* __restrict__ out,
    const int* __restrict__ list_tok, const float* __restrict__ list_prob,
    const int* __restrict__ meta) {
    int e = blockIdx.z;
    int cnt = meta[e];
    int m0 = blockIdx.y * 128;
    if (m0 >= cnt) return;
    int bs = meta[16 + e];
    int n0 = blockIdx.x * 128;

    __shared__ unsigned short sA[128 * 32];
    __shared__ unsigned short sB[128 * 32];

    int tid = threadIdx.x;
    int row = tid >> 1;
    int half = tid & 1;
    int colb = half * 16;

    int r = m0 + row;
    if (r >= cnt) r = cnt - 1;
    const unsigned short* aptr = hidden + (size_t)(bs + r) * Ff + colb;
    const WT* bptr = W3 + ((size_t)e * Dd + n0 + row) * Ff + colb;

    int lane = tid & 63;
    int w = tid >> 6;
    int wm = w >> 1, wn = w & 1;
    int lane15 = lane & 15, quad = lane >> 4;

    floatx4 acc[4][4] = {};

    unsigned short* sAw = &sA[row * 32 + colb];
    unsigned short* sBw = &sB[row * 32 + colb];
    const unsigned short* sAr = &sA[(wm * 64 + lane15) * 32 + quad * 8];
    const unsigned short* sBr = &sB[(wn * 64 + lane15) * 32 + quad * 8];

    for (int k0 = 0; k0 < Ff; k0 += 32) {
        stage16(sAw, aptr + k0);
        stage16(sBw, bptr + k0);
        __syncthreads();
        short8 af[4], bf[4];
#pragma unroll
        for (int i = 0; i < 4; i++) {
            af[i] = *reinterpret_cast<const short8*>(sAr + i * 16 * 32);
            bf[i] = *reinterpret_cast<const short8*>(sBr + i * 16 * 32);
        }
#pragma unroll
        for (int mi = 0; mi < 4; mi++)
#pragma unroll
            for (int ni = 0; ni < 4; ni++)
                acc[mi][ni] = __builtin_amdgcn_mfma_f32_16x16x32_bf16(af[mi], bf[ni], acc[mi][ni], 0, 0, 0);
        __syncthreads();
    }

#pragma unroll
    for (int mi = 0; mi < 4; mi++) {
#pragma unroll
        for (int i = 0; i < 4; i++) {
            int rr = m0 + wm * 64 + mi * 16 + quad * 4 + i;
            if (rr < cnt) {
                int pos = bs + rr;
                int tok = list_tok[pos];
                float p = list_prob[pos];
                float* op = out + (size_t)tok * Dd + n0 + wn * 64;
#pragma unroll
                for (int ni = 0; ni < 4; ni++)
                    atomicAdd(&op[ni * 16 + lane15], p * acc[mi][ni][i]);
            }
        }
    }
}

// ---------------- host launch ----------------
extern "C" void kernel_launch(void* const* d_in, const int* in_sizes, int n_in,
                              void* d_out, int out_size, void* d_ws, size_t ws_size,
                              hipStream_t stream) {
    const float* x  = (const float*)d_in[0];
    const float* Wg = (const float*)d_in[1];
    const float* W1 = (const float*)d_in[2];
    const float* W2 = (const float*)d_in[3];
    const float* W3 = (const float*)d_in[4];
    float* out = (float*)d_out;

    char* ws = (char*)d_ws;
    size_t off = 0;
    auto alloc = [&](size_t bytes) -> char* {
        size_t o = off;
        off += (bytes + 255) & ~(size_t)255;
        return ws + o;
    };

    int* meta = (int*)alloc(64 * sizeof(int));
    int* tok_idx = (int*)alloc((size_t)TOK * 2 * sizeof(int));
    float* tok_prob = (float*)alloc((size_t)TOK * 2 * sizeof(float));
    int* list_tok = (int*)alloc((size_t)PAIRS * sizeof(int));
    float* list_prob = (float*)alloc((size_t)PAIRS * sizeof(float));
    unsigned short* xb = (unsigned short*)alloc((size_t)TOK * Dd * sizeof(unsigned short));
    unsigned short* hidden = (unsigned short*)alloc((size_t)PAIRS * Ff * sizeof(unsigned short));

    size_t wbytes = (size_t)Ee * Ff * Dd * sizeof(unsigned short);
    bool pre = (ws_size >= off + 3 * wbytes + 4096);
    unsigned short *W1b = nullptr, *W2b = nullptr, *W3b = nullptr;
    if (pre) {
        W1b = (unsigned short*)alloc(wbytes);
        W2b = (unsigned short*)alloc(wbytes);
        W3b = (unsigned short*)alloc(wbytes);
    }

    int n4out = out_size / 4;
    zero_kernel<<<dim3((n4out + 255) / 256), dim3(256), 0, stream>>>(out, n4out, meta);
    gating_kernel<<<dim3(TOK / 4), dim3(256), 0, stream>>>(x, Wg, tok_idx, tok_prob, meta);
    scan_kernel<<<dim3(1), dim3(1), 0, stream>>>(meta);
    scatter_kernel<<<dim3(TOK / 256), dim3(256), 0, stream>>>(tok_idx, tok_prob, meta, list_tok, list_prob);

    int xn4 = TOK * Dd / 4;
    cvt_kernel<<<dim3((xn4 + 255) / 256), dim3(256), 0, stream>>>(x, xb, xn4);

    if (pre) {
        int wn4 = Ee * Ff * Dd / 4;
        cvt_kernel<<<dim3((wn4 + 255) / 256), dim3(256), 0, stream>>>(W1, W1b, wn4);
        cvt_kernel<<<dim3((wn4 + 255) / 256), dim3(256), 0, stream>>>(W2, W2b, wn4);
        cvt_kernel<<<dim3((wn4 + 255) / 256), dim3(256), 0, stream>>>(W3, W3b, wn4);
        gemm1_kernel<unsigned short><<<dim3(Ff / 128, 32, Ee), dim3(256), 0, stream>>>(
            xb, W1b, W2b, hidden, list_tok, meta);
        gemm2_kernel<unsigned short><<<dim3(Dd / 128, 32, Ee), dim3(256), 0, stream>>>(
            hidden, W3b, out, list_tok, list_prob, meta);
    } else {
        gemm1_kernel<float><<<dim3(Ff / 128, 32, Ee), dim3(256), 0, stream>>>(
            xb, W1, W2, hidden, list_tok, meta);
        gemm2_kernel<float><<<dim3(Dd / 128, 32, Ee), dim3(256), 0, stream>>>(
            hidden, W3, out, list_tok, list_prob, meta);
    }
}